// Round 1
// baseline (53.508 us; speedup 1.0000x reference)
//
#include <hip/hip_runtime.h>

// Problem constants (from reference): B=2, L=8192, D=1024, f32 in/out.
#define BB 2
#define LL 8192
#define DD 1024
#define NC 128   // number of time chunks
#define TT 64    // chunk length = LL/NC  (power of two; log2 = 6)

// ph[d] = exp(-(pr^2+pi^2)) * exp(i*atan2(pi,pr))
__device__ __forceinline__ void compute_ph(const float* __restrict__ pr_,
                                           const float* __restrict__ pi_,
                                           int d, float& phr, float& phi) {
    float pr = pr_[d], pi = pi_[d];
    float r2 = fmaf(pr, pr, pi * pi);
    float mag = expf(-r2);
    float r = sqrtf(r2);
    if (r > 1e-30f) {
        float inv = mag / r;
        phr = pr * inv;
        phi = pi * inv;
    } else {
        phr = mag;  // atan2(0,0)=0 -> phase 1+0i
        phi = 0.0f;
    }
}

// Pass 1: per-chunk end state with zero initial state.
__global__ __launch_bounds__(256) void k_partial(
    const float* __restrict__ x,
    const float* __restrict__ pr, const float* __restrict__ pi,
    const float* __restrict__ qr, const float* __restrict__ qi,
    float2* __restrict__ partial)
{
    int d = blockIdx.x * 256 + threadIdx.x;
    int j = blockIdx.y;
    int b = blockIdx.z;
    float phr, phi; compute_ph(pr, pi, d, phr, phi);
    float qre = qr[d], qim = qi[d];
    const float* xp = x + ((size_t)b * LL + (size_t)j * TT) * DD + d;
    float sr = 0.f, si = 0.f;
    #pragma unroll 16
    for (int t = 0; t < TT; ++t) {
        float xv = xp[(size_t)t * DD];
        float nr = fmaf(phr, sr, fmaf(-phi, si, qre * xv));
        float ni = fmaf(phi, sr, fmaf(phr, si, qim * xv));
        sr = nr; si = ni;
    }
    partial[((size_t)b * NC + j) * DD + d] = make_float2(sr, si);
}

// Pass 2 (tiny): serial combine across chunks; store each chunk's start state.
// S_0 = last[d];  S_{j+1} = ph^T * S_j + P_j
__global__ __launch_bounds__(256) void k_scan(
    const float* __restrict__ pr, const float* __restrict__ pi,
    const float* __restrict__ lr, const float* __restrict__ li,
    const float2* __restrict__ partial,
    float2* __restrict__ Sarr)
{
    int idx = blockIdx.x * 256 + threadIdx.x;  // b*DD + d
    int d = idx & (DD - 1);
    int b = idx >> 10;                          // DD = 1024 = 2^10
    if (b >= BB) return;
    float phr, phi; compute_ph(pr, pi, d, phr, phi);
    // ph^TT by repeated squaring (TT = 2^6)
    float ar = phr, ai = phi;
    #pragma unroll
    for (int k = 0; k < 6; ++k) {
        float nr = ar * ar - ai * ai;
        float ni = 2.f * ar * ai;
        ar = nr; ai = ni;
    }
    float sr = lr[d], si = li[d];
    for (int j = 0; j < NC; ++j) {
        size_t o = ((size_t)b * NC + j) * DD + d;
        Sarr[o] = make_float2(sr, si);
        float2 P = partial[o];
        float nr = fmaf(ar, sr, fmaf(-ai, si, P.x));
        float ni = fmaf(ai, sr, fmaf(ar, si, P.y));
        sr = nr; si = ni;
    }
}

// Pass 3: re-run each chunk from its true start state; emit Re(c).
__global__ __launch_bounds__(256) void k_final(
    const float* __restrict__ x,
    const float* __restrict__ pr, const float* __restrict__ pi,
    const float* __restrict__ qr, const float* __restrict__ qi,
    const float2* __restrict__ Sarr,
    float* __restrict__ out)
{
    int d = blockIdx.x * 256 + threadIdx.x;
    int j = blockIdx.y;
    int b = blockIdx.z;
    float phr, phi; compute_ph(pr, pi, d, phr, phi);
    float qre = qr[d], qim = qi[d];
    float2 S = Sarr[((size_t)b * NC + j) * DD + d];
    float sr = S.x, si = S.y;
    const float* xp = x + ((size_t)b * LL + (size_t)j * TT) * DD + d;
    float* op = out + ((size_t)b * LL + (size_t)j * TT) * DD + d;
    #pragma unroll 16
    for (int t = 0; t < TT; ++t) {
        float xv = xp[(size_t)t * DD];
        float nr = fmaf(phr, sr, fmaf(-phi, si, qre * xv));
        float ni = fmaf(phi, sr, fmaf(phr, si, qim * xv));
        sr = nr; si = ni;
        op[(size_t)t * DD] = sr;
    }
}

extern "C" void kernel_launch(void* const* d_in, const int* in_sizes, int n_in,
                              void* d_out, int out_size, void* d_ws, size_t ws_size,
                              hipStream_t stream) {
    const float* x  = (const float*)d_in[0];
    const float* pr = (const float*)d_in[1];
    const float* pi = (const float*)d_in[2];
    const float* qr = (const float*)d_in[3];
    const float* qi = (const float*)d_in[4];
    const float* lr = (const float*)d_in[5];
    const float* li = (const float*)d_in[6];
    float* out = (float*)d_out;

    float2* partial = (float2*)d_ws;                       // BB*NC*DD float2 = 2 MB
    float2* Sarr    = partial + (size_t)BB * NC * DD;      // 2 MB more

    dim3 grid_big(DD / 256, NC, BB);   // 4 x 128 x 2 = 1024 blocks
    k_partial<<<grid_big, 256, 0, stream>>>(x, pr, pi, qr, qi, partial);
    k_scan<<<(BB * DD) / 256, 256, 0, stream>>>(pr, pi, lr, li, partial, Sarr);
    k_final<<<grid_big, 256, 0, stream>>>(x, pr, pi, qr, qi, Sarr, out);
}

// Round 3
// 46.072 us; speedup vs baseline: 1.1614x; 1.1614x over previous
//
#include <hip/hip_runtime.h>

// Problem constants (from reference): B=2, L=8192, D=1024, f32 in/out.
#define BB 2
#define LL 8192
#define DD 1024
#define NC 128   // number of time chunks
#define TT 64    // chunk length = LL/NC (2^6)

// ph = exp(-(pr^2+pi^2)) * exp(i*atan2(pi,pr))
__device__ __forceinline__ void compute_ph(float pr, float pi, float& phr, float& phi) {
    float r2 = fmaf(pr, pr, pi * pi);
    float mag = expf(-r2);
    float r = sqrtf(r2);
    if (r > 1e-30f) {
        float inv = mag / r;
        phr = pr * inv;
        phi = pi * inv;
    } else {
        phr = mag;  // atan2(0,0)=0 -> phase 1+0i
        phi = 0.0f;
    }
}

// Pass 1: per-chunk end state with zero initial state.
__global__ __launch_bounds__(256) void k_partial(
    const float* __restrict__ x,
    const float* __restrict__ pr, const float* __restrict__ pi,
    const float* __restrict__ qr, const float* __restrict__ qi,
    float2* __restrict__ partial)
{
    int d = blockIdx.x * 256 + threadIdx.x;
    int j = blockIdx.y;
    int b = blockIdx.z;
    float phr, phi; compute_ph(pr[d], pi[d], phr, phi);
    float qre = qr[d], qim = qi[d];
    const float* xp = x + ((size_t)b * LL + (size_t)j * TT) * DD + d;
    float sr = 0.f, si = 0.f;
    #pragma unroll 16
    for (int t = 0; t < TT; ++t) {
        float xv = xp[(size_t)t * DD];
        float nr = fmaf(phr, sr, fmaf(-phi, si, qre * xv));
        float ni = fmaf(phi, sr, fmaf(phr, si, qim * xv));
        sr = nr; si = ni;
    }
    partial[((size_t)b * NC + j) * DD + d] = make_float2(sr, si);
}

// Pass 2: fold partials 0..j-1 (redundant per block, L2/L3-resident),
// then replay the chunk from the true start state and emit Re(state).
__global__ __launch_bounds__(256) void k_final(
    const float* __restrict__ x,
    const float* __restrict__ pr, const float* __restrict__ pi,
    const float* __restrict__ qr, const float* __restrict__ qi,
    const float* __restrict__ lr, const float* __restrict__ li,
    const float2* __restrict__ partial,
    float* __restrict__ out)
{
    int d = blockIdx.x * 256 + threadIdx.x;
    int j = blockIdx.y;
    int b = blockIdx.z;
    float phr, phi; compute_ph(pr[d], pi[d], phr, phi);
    float qre = qr[d], qim = qi[d];

    // a = ph^TT by repeated squaring (TT = 2^6)
    float ar = phr, ai = phi;
    #pragma unroll
    for (int k = 0; k < 6; ++k) {
        float nr = ar * ar - ai * ai;
        float ni = 2.f * ar * ai;
        ar = nr; ai = ni;
    }

    // fold partials 0..j-1:  S <- a*S + P_k, starting from S = last
    float Sr = lr[d], Si = li[d];
    const float2* pb = partial + (size_t)b * NC * DD + d;
    #pragma unroll 4
    for (int k = 0; k < j; ++k) {
        float2 P = pb[(size_t)k * DD];
        float nr = fmaf(ar, Sr, fmaf(-ai, Si, P.x));
        float ni = fmaf(ai, Sr, fmaf(ar, Si, P.y));
        Sr = nr; Si = ni;
    }

    // replay chunk from true start state; x is L3-resident after pass 1
    const size_t base = ((size_t)b * LL + (size_t)j * TT) * DD + d;
    const float* xp = x + base;
    float* op = out + base;
    #pragma unroll 16
    for (int t = 0; t < TT; ++t) {
        float xv = xp[(size_t)t * DD];
        float nr = fmaf(phr, Sr, fmaf(-phi, Si, qre * xv));
        float ni = fmaf(phi, Sr, fmaf(phr, Si, qim * xv));
        Sr = nr; Si = ni;
        op[(size_t)t * DD] = nr;
    }
}

extern "C" void kernel_launch(void* const* d_in, const int* in_sizes, int n_in,
                              void* d_out, int out_size, void* d_ws, size_t ws_size,
                              hipStream_t stream) {
    const float* x  = (const float*)d_in[0];
    const float* pr = (const float*)d_in[1];
    const float* pi = (const float*)d_in[2];
    const float* qr = (const float*)d_in[3];
    const float* qi = (const float*)d_in[4];
    const float* lr = (const float*)d_in[5];
    const float* li = (const float*)d_in[6];
    float* out = (float*)d_out;

    float2* partial = (float2*)d_ws;   // BB*NC*DD float2 = 2 MB

    dim3 grid(DD / 256, NC, BB);       // 4 x 128 x 2 = 1024 blocks
    k_partial<<<grid, 256, 0, stream>>>(x, pr, pi, qr, qi, partial);
    k_final<<<grid, 256, 0, stream>>>(x, pr, pi, qr, qi, lr, li, partial, out);
}